// Round 4
// baseline (1654.180 us; speedup 1.0000x reference)
//
#include <hip/hip_runtime.h>
#include <cstdint>
#include <cstddef>

#define KKSLOTS 25

typedef __attribute__((ext_vector_type(8))) short short8;
typedef __attribute__((ext_vector_type(4))) float f32x4;
typedef __attribute__((ext_vector_type(4))) unsigned short us4;

__device__ __forceinline__ unsigned short f2bf(float f) {
    unsigned u = __float_as_uint(f);
    u += 0x7FFF + ((u >> 16) & 1);           // RNE
    return (unsigned short)(u >> 16);
}
__device__ __forceinline__ float bf2f(unsigned short b) {
    return __uint_as_float((unsigned)b << 16);
}

// async global->LDS, 16B per lane. LDS dest is wave-uniform base + lane*16.
__device__ __forceinline__ void gload16(const void* g, void* l) {
    __builtin_amdgcn_global_load_lds(
        (const __attribute__((address_space(1))) unsigned*)g,
        (__attribute__((address_space(3))) unsigned*)l, 16, 0, 0);
}

// ===========================================================================
// CSR build: counting sort of edges by dst, with precomputed spline records.
// Record (int4): {src, packed_slots(4x5bit), bits(f0), bits(f1)}
// ===========================================================================
__global__ void csr_count_kernel(const int* __restrict__ dst, int* __restrict__ cnt, int E) {
    int e = blockIdx.x * blockDim.x + threadIdx.x;
    if (e < E) atomicAdd(&cnt[dst[e]], 1);
}

#define SCAN_B 256
__global__ __launch_bounds__(SCAN_B) void scan1_kernel(const int* __restrict__ cnt,
                                                       int* __restrict__ off,
                                                       int* __restrict__ bsum, int N) {
    __shared__ int tmp[SCAN_B];
    int g = blockIdx.x * SCAN_B + threadIdx.x;
    int v = (g < N) ? cnt[g] : 0;
    tmp[threadIdx.x] = v;
    __syncthreads();
    for (int d = 1; d < SCAN_B; d <<= 1) {
        int t = (threadIdx.x >= d) ? tmp[threadIdx.x - d] : 0;
        __syncthreads();
        tmp[threadIdx.x] += t;
        __syncthreads();
    }
    if (g < N) off[g] = tmp[threadIdx.x] - v;      // exclusive
    if (threadIdx.x == SCAN_B - 1) bsum[blockIdx.x] = tmp[threadIdx.x];
}

__global__ __launch_bounds__(SCAN_B) void scan2_kernel(int* __restrict__ bsum, int nb) {
    __shared__ int tmp[SCAN_B];
    int v = (threadIdx.x < nb) ? bsum[threadIdx.x] : 0;
    tmp[threadIdx.x] = v;
    __syncthreads();
    for (int d = 1; d < SCAN_B; d <<= 1) {
        int t = (threadIdx.x >= d) ? tmp[threadIdx.x - d] : 0;
        __syncthreads();
        tmp[threadIdx.x] += t;
        __syncthreads();
    }
    if (threadIdx.x < nb) bsum[threadIdx.x] = tmp[threadIdx.x] - v;  // exclusive
}

__global__ void scan3_kernel(int* __restrict__ off, const int* __restrict__ bsum, int N) {
    int g = blockIdx.x * SCAN_B + threadIdx.x;
    if (g < N) off[g] += bsum[blockIdx.x];
}

// After this kernel: off[n] == end(n); start(n) = (n==0) ? 0 : off[n-1].
__global__ void csr_fill_kernel(const int* __restrict__ src, const int* __restrict__ dst,
                                const float* __restrict__ pseudo,
                                int* __restrict__ off, int4* __restrict__ rec, int E) {
    int e = blockIdx.x * blockDim.x + threadIdx.x;
    if (e >= E) return;
    int d = dst[e];
    int p = atomicAdd(&off[d], 1);
    float v0 = pseudo[2 * e + 0] * 4.0f;
    float v1 = pseudo[2 * e + 1] * 4.0f;
    float fl0 = floorf(v0), fl1 = floorf(v1);
    float f0 = v0 - fl0, f1 = v1 - fl1;
    int b0 = (int)fl0, b1 = (int)fl1;
    int i0a = min(max(b0, 0), 4),     i1a = min(max(b1, 0), 4);
    int i0b = min(max(b0 + 1, 0), 4), i1b = min(max(b1 + 1, 0), 4);
    int s00 = i0a * 5 + i1a;
    int s01 = i0a * 5 + i1b;
    int s10 = i0b * 5 + i1a;
    int s11 = i0b * 5 + i1b;
    int packed = s00 | (s01 << 5) | (s10 << 10) | (s11 << 15);
    int4 r;
    r.x = src[e];
    r.y = packed;
    r.z = __float_as_int(f0);
    r.w = __float_as_int(f1);
    rec[p] = r;
}

// ===========================================================================
// fp32 -> bf16 elementwise
// ===========================================================================
__global__ void to_bf16_kernel(const float* __restrict__ in, unsigned short* __restrict__ out, int n) {
    int i = blockIdx.x * 256 + threadIdx.x;
    if (i < n) out[i] = f2bf(in[i]);
}

// ===========================================================================
// build WT[OP][KP] bf16 = transpose of [W ; root] padded with zeros.
// ===========================================================================
template<int KP, int I, int O, int OP>
__global__ void build_wt_kernel(const float* __restrict__ W, const float* __restrict__ root,
                                unsigned short* __restrict__ WT) {
    int idx = blockIdx.x * 256 + threadIdx.x;
    if (idx >= OP * KP) return;
    int o = idx / KP, k = idx - o * KP;
    float v = 0.0f;
    if (o < O) {
        if (k < KKSLOTS * I) v = W[(size_t)k * O + o];
        else if (k < (KKSLOTS + 1) * I) v = root[(size_t)(k - KKSLOTS * I) * O + o];
    }
    WT[idx] = f2bf(v);
}

// ===========================================================================
// segmented accumulation over dst-sorted edges, NODE-ALIGNED wave ranges.
// v5: LDS accumulate is ds_add_f32 (fire-and-forget atomicAdd) -- the
// la[idx] += v RMW form forced conservative lgkmcnt waits between edges
// (compiler can't disambiguate runtime slot indices), serializing on LDS
// round-trip latency (round-3 profile: 80us, VALU 48%, nothing saturated).
// Atomics have no read on the critical path; only drain is before flush.
// Contention is zero: wave-private tile, lane-distinct addresses.
// ===========================================================================
template<int I>
__device__ __forceinline__ void edge_add(float* la, int lane, int4 r,
                                         const unsigned short* __restrict__ xb) {
    float f0 = __int_as_float(r.z), f1 = __int_as_float(r.w);
    float g0 = 1.0f - f0, g1 = 1.0f - f1;
    int pk = r.y;
    if constexpr (I == 64) {
        float xv = bf2f(xb[(size_t)r.x * 64 + lane]);
        atomicAdd(&la[((pk      ) & 31) * 64 + lane], g0 * g1 * xv);
        atomicAdd(&la[((pk >> 5 ) & 31) * 64 + lane], g0 * f1 * xv);
        atomicAdd(&la[((pk >> 10) & 31) * 64 + lane], f0 * g1 * xv);
        atomicAdd(&la[((pk >> 15) & 31) * 64 + lane], f0 * f1 * xv);
    } else if constexpr (I == 32) {
        int ch = lane & 31, half = lane >> 5;
        float xv = bf2f(xb[(size_t)r.x * 32 + ch]);
        float wA = half ? f0 : g0;
        int sh = half * 10;
        int sA = (pk >> sh) & 31, sB = (pk >> (sh + 5)) & 31;
        atomicAdd(&la[sA * 32 + ch], wA * g1 * xv);
        atomicAdd(&la[sB * 32 + ch], wA * f1 * xv);
    } else {  // I == 8, lanes 0..31 active
        int ch = lane & 7, corner = (lane >> 3) & 3;
        if (lane < 32) {
            float xv = bf2f(xb[(size_t)r.x * 8 + ch]);
            int s = (pk >> (corner * 5)) & 31;
            float w = ((corner & 2) ? f0 : g0) * ((corner & 1) ? f1 : g1);
            atomicAdd(&la[s * 8 + ch], w * xv);
        }
    }
}

template<int I, int KP>
__global__ __launch_bounds__(256) void seg_accum_kernel(
        const unsigned short* __restrict__ xb, const int4* __restrict__ rec,
        const int* __restrict__ off, unsigned short* __restrict__ accB,
        int nlo, int nhi) {
    constexpr int SLOTS = KKSLOTS * I;
    __shared__ float la_all[4][SLOTS];
    int wline = threadIdx.x >> 6, lane = threadIdx.x & 63;
    float* la = la_all[wline];
    int wid = blockIdx.x * 4 + wline;
    int nwt = gridDim.x << 2;

    int e_lo = (nlo == 0) ? 0 : off[nlo - 1];
    int e_hi = off[nhi - 1];
    long long span = (long long)e_hi - e_lo;
    int t0 = e_lo + (int)(span * wid / nwt);
    int t1 = e_lo + (int)(span * (wid + 1) / nwt);

    int ns, ne;
    {   int lo = nlo, hi = nhi;
        while (lo < hi) { int m = (lo + hi) >> 1; if (off[m] > t0) hi = m; else lo = m + 1; }
        ns = (wid == 0) ? nlo : lo; }
    {   int lo = nlo, hi = nhi;
        while (lo < hi) { int m = (lo + hi) >> 1; if (off[m] > t1) hi = m; else lo = m + 1; }
        ne = (wid == nwt - 1) ? nhi : lo; }
    if (ns >= ne) return;

    for (int t = lane; t < SLOTS; t += 64) la[t] = 0.0f;
    int j = (ns == 0) ? 0 : off[ns - 1];
    for (int n = ns; n < ne; ++n) {
        int je = off[n];
        int jstart = j;
        while (j + 8 <= je) {
            int4 r0 = rec[j], r1 = rec[j + 1], r2 = rec[j + 2], r3 = rec[j + 3];
            int4 r4 = rec[j + 4], r5 = rec[j + 5], r6 = rec[j + 6], r7 = rec[j + 7];
            edge_add<I>(la, lane, r0, xb);
            edge_add<I>(la, lane, r1, xb);
            edge_add<I>(la, lane, r2, xb);
            edge_add<I>(la, lane, r3, xb);
            edge_add<I>(la, lane, r4, xb);
            edge_add<I>(la, lane, r5, xb);
            edge_add<I>(la, lane, r6, xb);
            edge_add<I>(la, lane, r7, xb);
            j += 8;
        }
        while (j + 4 <= je) {
            int4 r0 = rec[j], r1 = rec[j + 1], r2 = rec[j + 2], r3 = rec[j + 3];
            edge_add<I>(la, lane, r0, xb);
            edge_add<I>(la, lane, r1, xb);
            edge_add<I>(la, lane, r2, xb);
            edge_add<I>(la, lane, r3, xb);
            j += 4;
        }
        while (j < je) { edge_add<I>(la, lane, rec[j], xb); ++j; }

        // flush node n (compiler inserts lgkmcnt drain before the reads)
        float dinv = 1.0f / fmaxf((float)(je - jstart), 1.0f);
        unsigned short* drow = accB + (size_t)(n - nlo) * KP;
        for (int t = lane; t < SLOTS; t += 64) drow[t] = f2bf(la[t] * dinv);
        for (int t = SLOTS + lane; t < KP; t += 64) {
            int ii = t - SLOTS;
            drow[t] = (ii < I) ? xb[(size_t)n * I + ii] : (unsigned short)0;
        }
        for (int t = lane; t < SLOTS; t += 64) la[t] = 0.0f;
    }
}

// ===========================================================================
// MFMA contraction v4 (unchanged from round 3 -- it left the top-5):
// 8 waves/block, 64 nodes/block, A+B staged via global_load_lds width-16,
// double-buffered, swizzled source+read (T2 rule #21).
// ===========================================================================
template<int KP, int O, int OP>
__global__ __launch_bounds__(512) void contract_mfma_kernel(
        const unsigned short* __restrict__ accB, const unsigned short* __restrict__ WT,
        const float* __restrict__ bias, unsigned short* __restrict__ hout,
        int nlo, int nhi) {
    constexpr int OSUB = OP / 2;               // outputs per wave
    constexpr int NF = OSUB / 16;              // B frags / MFMAs per wave per step
    constexpr int NS = KP / 32;                // k-steps
    constexpr int BT = OP * 64;                // B tile bytes (rows=OP, 64B = 32 bf16)
    constexpr int AT = 64 * 64;                // A tile bytes (rows=64 nodes)
    __shared__ __attribute__((aligned(16))) char Bt[2][BT];
    __shared__ __attribute__((aligned(16))) char At[2][AT];

    int tid = threadIdx.x;
    int wv = tid >> 6, lane = tid & 63;
    int ng = wv & 3, oh = wv >> 2;
    int quad = lane >> 4, l16 = lane & 15;
    int n0 = nlo + blockIdx.x * 64;

    // ---- staging source addresses (inverse-swizzled; involution on bits 4-5)
    const char* WTc = (const char*)WT;
    const char* ACc = (const char*)accB;
    int pB = tid * 16;                         // linear LDS byte this thread fills (B)
    int rowB = pB >> 6;
    int colB = (pB & 63) ^ (((rowB >> 1) & 3) << 4);
    const char* bsrc = WTc + (size_t)rowB * (KP * 2) + colB;
    int pA = tid * 16;                         // linear LDS byte this thread fills (A)
    int rowA = pA >> 6;
    int arowA = min(n0 + rowA, nhi - 1) - nlo;
    int colA = (pA & 63) ^ (((rowA >> 1) & 3) << 4);
    const char* asrc = ACc + (size_t)arowA * (KP * 2) + colA;

    // ---- swizzled LDS read offsets (loop-invariant per lane)
    int rA = ng * 16 + l16;
    int aoff = rA * 64 + ((quad ^ ((rA >> 1) & 3)) << 4);
    int boff[NF];
    #pragma unroll
    for (int t = 0; t < NF; ++t) {
        int rB = oh * OSUB + t * 16 + l16;
        boff[t] = rB * 64 + ((quad ^ ((rB >> 1) & 3)) << 4);
    }

    f32x4 acc[NF];
    #pragma unroll
    for (int t = 0; t < NF; ++t) acc[t] = (f32x4){0.0f, 0.0f, 0.0f, 0.0f};

    auto STAGE = [&](int buf, int k0) {
        int kb = k0 * 2;
        if (pB < BT) gload16(bsrc + kb, &Bt[buf][wv << 10]);
        if (pA < AT) gload16(asrc + kb, &At[buf][wv << 10]);
    };

    STAGE(0, 0);
    __syncthreads();                           // buf0 staged (vmcnt drain + barrier)

    for (int s = 0; s < NS; ++s) {
        int cur = s & 1;
        if (s + 1 < NS) STAGE(cur ^ 1, (s + 1) * 32);   // in flight during compute
        short8 a = *(const short8*)(At[cur] + aoff);
        #pragma unroll
        for (int t = 0; t < NF; ++t) {
            short8 b = *(const short8*)(Bt[cur] + boff[t]);
            acc[t] = __builtin_amdgcn_mfma_f32_16x16x32_bf16(a, b, acc[t], 0, 0, 0);
        }
        __syncthreads();                       // drains stage; orders reads vs overwrite
    }

    // ---- epilogue: bias + ELU, bf16 store (wave-owned tile, no reduction)
    #pragma unroll
    for (int t = 0; t < NF; ++t) {
        int o = oh * OSUB + t * 16 + l16;
        if (o >= O) continue;
        float bs = bias[o];
        #pragma unroll
        for (int r = 0; r < 4; ++r) {
            int n = n0 + ng * 16 + quad * 4 + r;
            if (n >= nhi) continue;
            float v = acc[t][r] + bs;
            v = (v > 0.0f) ? v : expm1f(v);
            hout[(size_t)n * OP + o] = f2bf(v);
        }
    }
}

// ===========================================================================
// segmented graph sum (batch sorted, h3 bf16 stride 128) + count + head
// ===========================================================================
#define GS_CH 128
__global__ __launch_bounds__(128) void graph_reduce_kernel(
        const unsigned short* __restrict__ h3, const int* __restrict__ batch,
        float* __restrict__ g, int N) {
    int o = threadIdx.x;
    if (o >= 124) return;
    int n0 = blockIdx.x * GS_CH;
    int n1 = min(n0 + GS_CH, N);
    float local = 0.0f;
    int cur_b = batch[n0];
    for (int n = n0; n < n1; ++n) {
        int b = batch[n];
        if (b != cur_b) {
            atomicAdd(&g[cur_b * 124 + o], local);
            local = 0.0f;
            cur_b = b;
        }
        local += bf2f(h3[(size_t)n * 128 + o]);
    }
    atomicAdd(&g[cur_b * 124 + o], local);
}

__global__ __launch_bounds__(256) void batch_count_kernel(
        const int* __restrict__ batch, float* __restrict__ cnt, int N) {
    __shared__ int hist[64];
    int tid = threadIdx.x;
    if (tid < 64) hist[tid] = 0;
    __syncthreads();
    int n = blockIdx.x * blockDim.x + tid;
    if (n < N) atomicAdd(&hist[batch[n]], 1);
    __syncthreads();
    if (tid < 64 && hist[tid] > 0) atomicAdd(&cnt[tid], (float)hist[tid]);
}

__global__ void head_kernel(const float* __restrict__ g, const float* __restrict__ cnt,
                            const float* __restrict__ fcw, const float* __restrict__ fcb,
                            float* __restrict__ out) {
    __shared__ float logits[32];
    __shared__ float red[2];
    int b = blockIdx.x;
    int o = threadIdx.x;
    float c = fmaxf(cnt[b], 1.0f);
    if (o < 30) {
        float a = fcb[o];
        for (int i = 0; i < 124; ++i)
            a = fmaf(g[b * 124 + i] / c, fcw[i * 30 + o], a);
        logits[o] = a;
    }
    __syncthreads();
    if (o == 0) {
        float m = -1e30f;
        for (int j = 0; j < 30; ++j) m = fmaxf(m, logits[j]);
        float s = 0.0f;
        for (int j = 0; j < 30; ++j) s += expf(logits[j] - m);
        red[0] = m;
        red[1] = logf(s);
    }
    __syncthreads();
    if (o < 30) out[b * 30 + o] = logits[o] - red[0] - red[1];
}

// ---------------------------------------------------------------------------
// per-layer driver (node-chunked so acc fits whatever ws_size allows)
// ---------------------------------------------------------------------------
template<int I, int O, int OP>
static void run_layer(const unsigned short* hb, const unsigned short* WT, const float* bias,
                      unsigned short* hout, unsigned short* accB,
                      const int4* rec, const int* off,
                      int N, size_t avail, hipStream_t stream) {
    constexpr int KP = ((26 * I + 31) / 32) * 32;
    size_t perNode = (size_t)KP * 2;
    size_t maxNodesS = avail / perNode;
    int maxNodes = (maxNodesS > (size_t)N) ? N : (int)maxNodesS;
    maxNodes &= ~63;
    if (maxNodes < 64) maxNodes = 64;
    for (int nlo = 0; nlo < N; nlo += maxNodes) {
        int nhi = nlo + maxNodes;
        if (nhi > N) nhi = N;
        int cn = nhi - nlo;
        seg_accum_kernel<I, KP><<<1536, 256, 0, stream>>>(hb, rec, off, accB, nlo, nhi);
        contract_mfma_kernel<KP, O, OP><<<(cn + 63) / 64, 512, 0, stream>>>(
            accB, WT, bias, hout, nlo, nhi);
    }
}

extern "C" void kernel_launch(void* const* d_in, const int* in_sizes, int n_in,
                              void* d_out, int out_size, void* d_ws, size_t ws_size,
                              hipStream_t stream) {
    const float* x      = (const float*)d_in[0];
    const int*   ei     = (const int*)  d_in[1];
    const float* pseudo = (const float*)d_in[2];
    const int*   batch  = (const int*)  d_in[3];
    const float* W1 = (const float*)d_in[4];
    const float* r1 = (const float*)d_in[5];
    const float* b1 = (const float*)d_in[6];
    const float* W2 = (const float*)d_in[7];
    const float* r2 = (const float*)d_in[8];
    const float* b2 = (const float*)d_in[9];
    const float* W3 = (const float*)d_in[10];
    const float* r3 = (const float*)d_in[11];
    const float* b3 = (const float*)d_in[12];
    const float* fcw = (const float*)d_in[13];
    const float* fcb = (const float*)d_in[14];

    int N = in_sizes[0] / 8;
    int E = in_sizes[1] / 2;
    const int* srcp = ei;
    const int* dstp = ei + E;

    constexpr int KP1 = 224, KP2 = 832, KP3 = 1664;   // all % 32 == 0

    // workspace carve (all pieces 16B-multiple)
    char* p = (char*)d_ws;
    unsigned short* xb  = (unsigned short*)p; p += (size_t)N * 8 * 2;
    unsigned short* h1  = (unsigned short*)p; p += (size_t)N * 32 * 2;
    unsigned short* h2  = (unsigned short*)p; p += (size_t)N * 64 * 2;
    unsigned short* h3  = (unsigned short*)p; p += (size_t)N * 128 * 2;  // stride 128 (padded)
    float* gbuf = (float*)p; p += 64 * 124 * 4;
    float* cntF = (float*)p; p += 256;
    int*   cntI = (int*)p;   p += ((size_t)N * 4 + 15) & ~15ULL;
    int*   off  = (int*)p;   p += ((size_t)N * 4 + 15) & ~15ULL;
    int*   bsum = (int*)p;   p += SCAN_B * 4;
    int4*  rec  = (int4*)p;  p += (size_t)E * 16;
    unsigned short* WT1 = (unsigned short*)p; p += (size_t)32  * KP1 * 2;
    unsigned short* WT2 = (unsigned short*)p; p += (size_t)64  * KP2 * 2;
    unsigned short* WT3 = (unsigned short*)p; p += (size_t)128 * KP3 * 2;
    unsigned short* accB = (unsigned short*)p;
    size_t used = (size_t)(p - (char*)d_ws);
    size_t avail = (ws_size > used) ? (ws_size - used) : 0;

    // zero: gbuf + cntF + cntI (contiguous)
    hipMemsetAsync(gbuf, 0, 64 * 124 * 4 + 256 + (((size_t)N * 4 + 15) & ~15ULL), stream);

    // CSR build
    int nb_scan = (N + SCAN_B - 1) / SCAN_B;
    csr_count_kernel<<<(E + 255) / 256, 256, 0, stream>>>(dstp, cntI, E);
    scan1_kernel<<<nb_scan, SCAN_B, 0, stream>>>(cntI, off, bsum, N);
    scan2_kernel<<<1, SCAN_B, 0, stream>>>(bsum, nb_scan);
    scan3_kernel<<<nb_scan, SCAN_B, 0, stream>>>(off, bsum, N);
    csr_fill_kernel<<<(E + 255) / 256, 256, 0, stream>>>(srcp, dstp, pseudo, off, rec, E);

    // conversions / weight prep
    to_bf16_kernel<<<(N * 8 + 255) / 256, 256, 0, stream>>>(x, xb, N * 8);
    build_wt_kernel<KP1, 8,  32,  32 ><<<(32  * KP1 + 255) / 256, 256, 0, stream>>>(W1, r1, WT1);
    build_wt_kernel<KP2, 32, 64,  64 ><<<(64  * KP2 + 255) / 256, 256, 0, stream>>>(W2, r2, WT2);
    build_wt_kernel<KP3, 64, 124, 128><<<(128 * KP3 + 255) / 256, 256, 0, stream>>>(W3, r3, WT3);

    run_layer<8,  32,  32 >(xb, WT1, b1, h1, accB, rec, off, N, avail, stream);
    run_layer<32, 64,  64 >(h1, WT2, b2, h2, accB, rec, off, N, avail, stream);
    run_layer<64, 124, 128>(h2, WT3, b3, h3, accB, rec, off, N, avail, stream);

    graph_reduce_kernel<<<(N + GS_CH - 1) / GS_CH, 128, 0, stream>>>(h3, batch, gbuf, N);
    batch_count_kernel<<<(N + 255) / 256, 256, 0, stream>>>(batch, cntF, N);
    head_kernel<<<64, 64, 0, stream>>>(gbuf, cntF, fcw, fcb, (float*)d_out);
}

// Round 6
// 511.788 us; speedup vs baseline: 3.2322x; 3.2322x over previous
//
#include <hip/hip_runtime.h>
#include <cstdint>
#include <cstddef>

#define KKSLOTS 25

typedef __attribute__((ext_vector_type(8))) short short8;
typedef __attribute__((ext_vector_type(4))) float f32x4;
typedef __attribute__((ext_vector_type(4))) unsigned short us4;

__device__ __forceinline__ unsigned short f2bf(float f) {
    unsigned u = __float_as_uint(f);
    u += 0x7FFF + ((u >> 16) & 1);           // RNE
    return (unsigned short)(u >> 16);
}
__device__ __forceinline__ float bf2f(unsigned short b) {
    return __uint_as_float((unsigned)b << 16);
}

// async global->LDS, 16B per lane. LDS dest is wave-uniform base + lane*16.
__device__ __forceinline__ void gload16(const void* g, void* l) {
    __builtin_amdgcn_global_load_lds(
        (const __attribute__((address_space(1))) unsigned*)g,
        (__attribute__((address_space(3))) unsigned*)l, 16, 0, 0);
}

// ===========================================================================
// CSR build: counting sort of edges by dst, with precomputed spline records.
// Record (int4): {src, packed_slots(4x5bit), bits(f0), bits(f1)}
// ===========================================================================
__global__ void csr_count_kernel(const int* __restrict__ dst, int* __restrict__ cnt, int E) {
    int e = blockIdx.x * blockDim.x + threadIdx.x;
    if (e < E) atomicAdd(&cnt[dst[e]], 1);
}

#define SCAN_B 256
__global__ __launch_bounds__(SCAN_B) void scan1_kernel(const int* __restrict__ cnt,
                                                       int* __restrict__ off,
                                                       int* __restrict__ bsum, int N) {
    __shared__ int tmp[SCAN_B];
    int g = blockIdx.x * SCAN_B + threadIdx.x;
    int v = (g < N) ? cnt[g] : 0;
    tmp[threadIdx.x] = v;
    __syncthreads();
    for (int d = 1; d < SCAN_B; d <<= 1) {
        int t = (threadIdx.x >= d) ? tmp[threadIdx.x - d] : 0;
        __syncthreads();
        tmp[threadIdx.x] += t;
        __syncthreads();
    }
    if (g < N) off[g] = tmp[threadIdx.x] - v;      // exclusive
    if (threadIdx.x == SCAN_B - 1) bsum[blockIdx.x] = tmp[threadIdx.x];
}

__global__ __launch_bounds__(SCAN_B) void scan2_kernel(int* __restrict__ bsum, int nb) {
    __shared__ int tmp[SCAN_B];
    int v = (threadIdx.x < nb) ? bsum[threadIdx.x] : 0;
    tmp[threadIdx.x] = v;
    __syncthreads();
    for (int d = 1; d < SCAN_B; d <<= 1) {
        int t = (threadIdx.x >= d) ? tmp[threadIdx.x - d] : 0;
        __syncthreads();
        tmp[threadIdx.x] += t;
        __syncthreads();
    }
    if (threadIdx.x < nb) bsum[threadIdx.x] = tmp[threadIdx.x] - v;  // exclusive
}

__global__ void scan3_kernel(int* __restrict__ off, const int* __restrict__ bsum, int N) {
    int g = blockIdx.x * SCAN_B + threadIdx.x;
    if (g < N) off[g] += bsum[blockIdx.x];
}

// After this kernel: off[n] == end(n); start(n) = (n==0) ? 0 : off[n-1].
__global__ void csr_fill_kernel(const int* __restrict__ src, const int* __restrict__ dst,
                                const float* __restrict__ pseudo,
                                int* __restrict__ off, int4* __restrict__ rec, int E) {
    int e = blockIdx.x * blockDim.x + threadIdx.x;
    if (e >= E) return;
    int d = dst[e];
    int p = atomicAdd(&off[d], 1);
    float v0 = pseudo[2 * e + 0] * 4.0f;
    float v1 = pseudo[2 * e + 1] * 4.0f;
    float fl0 = floorf(v0), fl1 = floorf(v1);
    float f0 = v0 - fl0, f1 = v1 - fl1;
    int b0 = (int)fl0, b1 = (int)fl1;
    int i0a = min(max(b0, 0), 4),     i1a = min(max(b1, 0), 4);
    int i0b = min(max(b0 + 1, 0), 4), i1b = min(max(b1 + 1, 0), 4);
    int s00 = i0a * 5 + i1a;
    int s01 = i0a * 5 + i1b;
    int s10 = i0b * 5 + i1a;
    int s11 = i0b * 5 + i1b;
    int packed = s00 | (s01 << 5) | (s10 << 10) | (s11 << 15);
    int4 r;
    r.x = src[e];
    r.y = packed;
    r.z = __float_as_int(f0);
    r.w = __float_as_int(f1);
    rec[p] = r;
}

// ===========================================================================
// fp32 -> bf16 elementwise
// ===========================================================================
__global__ void to_bf16_kernel(const float* __restrict__ in, unsigned short* __restrict__ out, int n) {
    int i = blockIdx.x * 256 + threadIdx.x;
    if (i < n) out[i] = f2bf(in[i]);
}

// ===========================================================================
// build WT[OP][KP] bf16 = transpose of [W ; root] padded with zeros.
// ===========================================================================
template<int KP, int I, int O, int OP>
__global__ void build_wt_kernel(const float* __restrict__ W, const float* __restrict__ root,
                                unsigned short* __restrict__ WT) {
    int idx = blockIdx.x * 256 + threadIdx.x;
    if (idx >= OP * KP) return;
    int o = idx / KP, k = idx - o * KP;
    float v = 0.0f;
    if (o < O) {
        if (k < KKSLOTS * I) v = W[(size_t)k * O + o];
        else if (k < (KKSLOTS + 1) * I) v = root[(size_t)(k - KKSLOTS * I) * O + o];
    }
    WT[idx] = f2bf(v);
}

// ===========================================================================
// segmented accumulation over dst-sorted edges, NODE-ALIGNED wave ranges.
// v6: plain fp32 += (round-4 LDS atomics lowered to flat/CAS: 10x regress,
// reverted), but PAIRED channels: each lane owns a channel PAIR and does
// float2 RMW -> ds_read_b64/ds_write_b64. Halves DS instruction count
// (round-3 arithmetic: ~46 of 82 cyc/edge was DS issue at 8 b32 ops/edge).
// Lane remap per I keeps all 4 corner slots on distinct lanes (s00..s11
// pairwise distinct since i0a!=i0b, i1a!=i1b for pseudo in [0,1)) -- no
// same-address lane collisions. Numerics identical to round 3 (same fp32
// adds in same order per (slot,ch)).
// ===========================================================================
template<int I>
__device__ __forceinline__ void edge_add(float* la, int lane, int4 r,
                                         const unsigned short* __restrict__ xb) {
    float f0 = __int_as_float(r.z), f1 = __int_as_float(r.w);
    float g0 = 1.0f - f0, g1 = 1.0f - f1;
    int pk = r.y;
    if constexpr (I == 64) {
        int c = lane & 31, half = lane >> 5;     // half 0: corners 00,01; half 1: 10,11
        unsigned xp = *(const unsigned*)&xb[(size_t)r.x * 64 + 2 * c];
        float x0 = bf2f((unsigned short)(xp & 0xffffu));
        float x1 = bf2f((unsigned short)(xp >> 16));
        float wA = half ? f0 : g0;
        int sh = half * 10;
        int sA = (pk >> sh) & 31, sB = (pk >> (sh + 5)) & 31;
        float wa = wA * g1, wb = wA * f1;
        float2* pa = (float2*)&la[sA * 64 + 2 * c];
        float2* pb = (float2*)&la[sB * 64 + 2 * c];
        float2 va = *pa; va.x += wa * x0; va.y += wa * x1; *pa = va;
        float2 vb = *pb; vb.x += wb * x0; vb.y += wb * x1; *pb = vb;
    } else if constexpr (I == 32) {
        int cp = lane & 15, corner = lane >> 4;  // 4 corners x 16 ch-pairs = 64 lanes
        unsigned xp = *(const unsigned*)&xb[(size_t)r.x * 32 + 2 * cp];
        float x0 = bf2f((unsigned short)(xp & 0xffffu));
        float x1 = bf2f((unsigned short)(xp >> 16));
        float w = ((corner & 2) ? f0 : g0) * ((corner & 1) ? f1 : g1);
        int s = (pk >> (corner * 5)) & 31;
        float2* pa = (float2*)&la[s * 32 + 2 * cp];
        float2 v = *pa; v.x += w * x0; v.y += w * x1; *pa = v;
    } else {  // I == 8: 4 corners x 4 ch-pairs = 16 active lanes
        if (lane < 16) {
            int cp = lane & 3, corner = lane >> 2;
            unsigned xp = *(const unsigned*)&xb[(size_t)r.x * 8 + 2 * cp];
            float x0 = bf2f((unsigned short)(xp & 0xffffu));
            float x1 = bf2f((unsigned short)(xp >> 16));
            float w = ((corner & 2) ? f0 : g0) * ((corner & 1) ? f1 : g1);
            int s = (pk >> (corner * 5)) & 31;
            float2* pa = (float2*)&la[s * 8 + 2 * cp];
            float2 v = *pa; v.x += w * x0; v.y += w * x1; *pa = v;
        }
    }
}

template<int I, int KP>
__global__ __launch_bounds__(256) void seg_accum_kernel(
        const unsigned short* __restrict__ xb, const int4* __restrict__ rec,
        const int* __restrict__ off, unsigned short* __restrict__ accB,
        int nlo, int nhi) {
    constexpr int SLOTS = KKSLOTS * I;
    __shared__ __attribute__((aligned(16))) float la_all[4][SLOTS];
    int wline = threadIdx.x >> 6, lane = threadIdx.x & 63;
    float* la = la_all[wline];
    int wid = blockIdx.x * 4 + wline;
    int nwt = gridDim.x << 2;

    int e_lo = (nlo == 0) ? 0 : off[nlo - 1];
    int e_hi = off[nhi - 1];
    long long span = (long long)e_hi - e_lo;
    int t0 = e_lo + (int)(span * wid / nwt);
    int t1 = e_lo + (int)(span * (wid + 1) / nwt);

    int ns, ne;
    {   int lo = nlo, hi = nhi;
        while (lo < hi) { int m = (lo + hi) >> 1; if (off[m] > t0) hi = m; else lo = m + 1; }
        ns = (wid == 0) ? nlo : lo; }
    {   int lo = nlo, hi = nhi;
        while (lo < hi) { int m = (lo + hi) >> 1; if (off[m] > t1) hi = m; else lo = m + 1; }
        ne = (wid == nwt - 1) ? nhi : lo; }
    if (ns >= ne) return;

    for (int t = lane; t < SLOTS; t += 64) la[t] = 0.0f;
    int j = (ns == 0) ? 0 : off[ns - 1];
    for (int n = ns; n < ne; ++n) {
        int je = off[n];
        int jstart = j;
        while (j + 4 <= je) {
            int4 r0 = rec[j], r1 = rec[j + 1], r2 = rec[j + 2], r3 = rec[j + 3];
            edge_add<I>(la, lane, r0, xb);
            edge_add<I>(la, lane, r1, xb);
            edge_add<I>(la, lane, r2, xb);
            edge_add<I>(la, lane, r3, xb);
            j += 4;
        }
        while (j < je) { edge_add<I>(la, lane, rec[j], xb); ++j; }

        // flush node n
        float dinv = 1.0f / fmaxf((float)(je - jstart), 1.0f);
        unsigned short* drow = accB + (size_t)(n - nlo) * KP;
        for (int t = lane; t < SLOTS; t += 64) drow[t] = f2bf(la[t] * dinv);
        for (int t = SLOTS + lane; t < KP; t += 64) {
            int ii = t - SLOTS;
            drow[t] = (ii < I) ? xb[(size_t)n * I + ii] : (unsigned short)0;
        }
        for (int t = lane; t < SLOTS; t += 64) la[t] = 0.0f;
    }
}

// ===========================================================================
// MFMA contraction v4 (unchanged from round 3 -- it left the top-5):
// 8 waves/block, 64 nodes/block, A+B staged via global_load_lds width-16,
// double-buffered, swizzled source+read (T2 rule #21).
// ===========================================================================
template<int KP, int O, int OP>
__global__ __launch_bounds__(512) void contract_mfma_kernel(
        const unsigned short* __restrict__ accB, const unsigned short* __restrict__ WT,
        const float* __restrict__ bias, unsigned short* __restrict__ hout,
        int nlo, int nhi) {
    constexpr int OSUB = OP / 2;               // outputs per wave
    constexpr int NF = OSUB / 16;              // B frags / MFMAs per wave per step
    constexpr int NS = KP / 32;                // k-steps
    constexpr int BT = OP * 64;                // B tile bytes (rows=OP, 64B = 32 bf16)
    constexpr int AT = 64 * 64;                // A tile bytes (rows=64 nodes)
    __shared__ __attribute__((aligned(16))) char Bt[2][BT];
    __shared__ __attribute__((aligned(16))) char At[2][AT];

    int tid = threadIdx.x;
    int wv = tid >> 6, lane = tid & 63;
    int ng = wv & 3, oh = wv >> 2;
    int quad = lane >> 4, l16 = lane & 15;
    int n0 = nlo + blockIdx.x * 64;

    // ---- staging source addresses (inverse-swizzled; involution on bits 4-5)
    const char* WTc = (const char*)WT;
    const char* ACc = (const char*)accB;
    int pB = tid * 16;                         // linear LDS byte this thread fills (B)
    int rowB = pB >> 6;
    int colB = (pB & 63) ^ (((rowB >> 1) & 3) << 4);
    const char* bsrc = WTc + (size_t)rowB * (KP * 2) + colB;
    int pA = tid * 16;                         // linear LDS byte this thread fills (A)
    int rowA = pA >> 6;
    int arowA = min(n0 + rowA, nhi - 1) - nlo;
    int colA = (pA & 63) ^ (((rowA >> 1) & 3) << 4);
    const char* asrc = ACc + (size_t)arowA * (KP * 2) + colA;

    // ---- swizzled LDS read offsets (loop-invariant per lane)
    int rA = ng * 16 + l16;
    int aoff = rA * 64 + ((quad ^ ((rA >> 1) & 3)) << 4);
    int boff[NF];
    #pragma unroll
    for (int t = 0; t < NF; ++t) {
        int rB = oh * OSUB + t * 16 + l16;
        boff[t] = rB * 64 + ((quad ^ ((rB >> 1) & 3)) << 4);
    }

    f32x4 acc[NF];
    #pragma unroll
    for (int t = 0; t < NF; ++t) acc[t] = (f32x4){0.0f, 0.0f, 0.0f, 0.0f};

    auto STAGE = [&](int buf, int k0) {
        int kb = k0 * 2;
        if (pB < BT) gload16(bsrc + kb, &Bt[buf][wv << 10]);
        if (pA < AT) gload16(asrc + kb, &At[buf][wv << 10]);
    };

    STAGE(0, 0);
    __syncthreads();                           // buf0 staged (vmcnt drain + barrier)

    for (int s = 0; s < NS; ++s) {
        int cur = s & 1;
        if (s + 1 < NS) STAGE(cur ^ 1, (s + 1) * 32);   // in flight during compute
        short8 a = *(const short8*)(At[cur] + aoff);
        #pragma unroll
        for (int t = 0; t < NF; ++t) {
            short8 b = *(const short8*)(Bt[cur] + boff[t]);
            acc[t] = __builtin_amdgcn_mfma_f32_16x16x32_bf16(a, b, acc[t], 0, 0, 0);
        }
        __syncthreads();                       // drains stage; orders reads vs overwrite
    }

    // ---- epilogue: bias + ELU, bf16 store (wave-owned tile, no reduction)
    #pragma unroll
    for (int t = 0; t < NF; ++t) {
        int o = oh * OSUB + t * 16 + l16;
        if (o >= O) continue;
        float bs = bias[o];
        #pragma unroll
        for (int r = 0; r < 4; ++r) {
            int n = n0 + ng * 16 + quad * 4 + r;
            if (n >= nhi) continue;
            float v = acc[t][r] + bs;
            v = (v > 0.0f) ? v : expm1f(v);
            hout[(size_t)n * OP + o] = f2bf(v);
        }
    }
}

// ===========================================================================
// segmented graph sum (batch sorted, h3 bf16 stride 128) + count + head
// ===========================================================================
#define GS_CH 128
__global__ __launch_bounds__(128) void graph_reduce_kernel(
        const unsigned short* __restrict__ h3, const int* __restrict__ batch,
        float* __restrict__ g, int N) {
    int o = threadIdx.x;
    if (o >= 124) return;
    int n0 = blockIdx.x * GS_CH;
    int n1 = min(n0 + GS_CH, N);
    float local = 0.0f;
    int cur_b = batch[n0];
    for (int n = n0; n < n1; ++n) {
        int b = batch[n];
        if (b != cur_b) {
            atomicAdd(&g[cur_b * 124 + o], local);
            local = 0.0f;
            cur_b = b;
        }
        local += bf2f(h3[(size_t)n * 128 + o]);
    }
    atomicAdd(&g[cur_b * 124 + o], local);
}

__global__ __launch_bounds__(256) void batch_count_kernel(
        const int* __restrict__ batch, float* __restrict__ cnt, int N) {
    __shared__ int hist[64];
    int tid = threadIdx.x;
    if (tid < 64) hist[tid] = 0;
    __syncthreads();
    int n = blockIdx.x * blockDim.x + tid;
    if (n < N) atomicAdd(&hist[batch[n]], 1);
    __syncthreads();
    if (tid < 64 && hist[tid] > 0) atomicAdd(&cnt[tid], (float)hist[tid]);
}

__global__ void head_kernel(const float* __restrict__ g, const float* __restrict__ cnt,
                            const float* __restrict__ fcw, const float* __restrict__ fcb,
                            float* __restrict__ out) {
    __shared__ float logits[32];
    __shared__ float red[2];
    int b = blockIdx.x;
    int o = threadIdx.x;
    float c = fmaxf(cnt[b], 1.0f);
    if (o < 30) {
        float a = fcb[o];
        for (int i = 0; i < 124; ++i)
            a = fmaf(g[b * 124 + i] / c, fcw[i * 30 + o], a);
        logits[o] = a;
    }
    __syncthreads();
    if (o == 0) {
        float m = -1e30f;
        for (int j = 0; j < 30; ++j) m = fmaxf(m, logits[j]);
        float s = 0.0f;
        for (int j = 0; j < 30; ++j) s += expf(logits[j] - m);
        red[0] = m;
        red[1] = logf(s);
    }
    __syncthreads();
    if (o < 30) out[b * 30 + o] = logits[o] - red[0] - red[1];
}

// ---------------------------------------------------------------------------
// per-layer driver (node-chunked so acc fits whatever ws_size allows)
// ---------------------------------------------------------------------------
template<int I, int O, int OP>
static void run_layer(const unsigned short* hb, const unsigned short* WT, const float* bias,
                      unsigned short* hout, unsigned short* accB,
                      const int4* rec, const int* off,
                      int N, size_t avail, hipStream_t stream) {
    constexpr int KP = ((26 * I + 31) / 32) * 32;
    size_t perNode = (size_t)KP * 2;
    size_t maxNodesS = avail / perNode;
    int maxNodes = (maxNodesS > (size_t)N) ? N : (int)maxNodesS;
    maxNodes &= ~63;
    if (maxNodes < 64) maxNodes = 64;
    for (int nlo = 0; nlo < N; nlo += maxNodes) {
        int nhi = nlo + maxNodes;
        if (nhi > N) nhi = N;
        int cn = nhi - nlo;
        seg_accum_kernel<I, KP><<<1536, 256, 0, stream>>>(hb, rec, off, accB, nlo, nhi);
        contract_mfma_kernel<KP, O, OP><<<(cn + 63) / 64, 512, 0, stream>>>(
            accB, WT, bias, hout, nlo, nhi);
    }
}

extern "C" void kernel_launch(void* const* d_in, const int* in_sizes, int n_in,
                              void* d_out, int out_size, void* d_ws, size_t ws_size,
                              hipStream_t stream) {
    const float* x      = (const float*)d_in[0];
    const int*   ei     = (const int*)  d_in[1];
    const float* pseudo = (const float*)d_in[2];
    const int*   batch  = (const int*)  d_in[3];
    const float* W1 = (const float*)d_in[4];
    const float* r1 = (const float*)d_in[5];
    const float* b1 = (const float*)d_in[6];
    const float* W2 = (const float*)d_in[7];
    const float* r2 = (const float*)d_in[8];
    const float* b2 = (const float*)d_in[9];
    const float* W3 = (const float*)d_in[10];
    const float* r3 = (const float*)d_in[11];
    const float* b3 = (const float*)d_in[12];
    const float* fcw = (const float*)d_in[13];
    const float* fcb = (const float*)d_in[14];

    int N = in_sizes[0] / 8;
    int E = in_sizes[1] / 2;
    const int* srcp = ei;
    const int* dstp = ei + E;

    constexpr int KP1 = 224, KP2 = 832, KP3 = 1664;   // all % 32 == 0

    // workspace carve (all pieces 16B-multiple)
    char* p = (char*)d_ws;
    unsigned short* xb  = (unsigned short*)p; p += (size_t)N * 8 * 2;
    unsigned short* h1  = (unsigned short*)p; p += (size_t)N * 32 * 2;
    unsigned short* h2  = (unsigned short*)p; p += (size_t)N * 64 * 2;
    unsigned short* h3  = (unsigned short*)p; p += (size_t)N * 128 * 2;  // stride 128 (padded)
    float* gbuf = (float*)p; p += 64 * 124 * 4;
    float* cntF = (float*)p; p += 256;
    int*   cntI = (int*)p;   p += ((size_t)N * 4 + 15) & ~15ULL;
    int*   off  = (int*)p;   p += ((size_t)N * 4 + 15) & ~15ULL;
    int*   bsum = (int*)p;   p += SCAN_B * 4;
    int4*  rec  = (int4*)p;  p += (size_t)E * 16;
    unsigned short* WT1 = (unsigned short*)p; p += (size_t)32  * KP1 * 2;
    unsigned short* WT2 = (unsigned short*)p; p += (size_t)64  * KP2 * 2;
    unsigned short* WT3 = (unsigned short*)p; p += (size_t)128 * KP3 * 2;
    unsigned short* accB = (unsigned short*)p;
    size_t used = (size_t)(p - (char*)d_ws);
    size_t avail = (ws_size > used) ? (ws_size - used) : 0;

    // zero: gbuf + cntF + cntI (contiguous)
    hipMemsetAsync(gbuf, 0, 64 * 124 * 4 + 256 + (((size_t)N * 4 + 15) & ~15ULL), stream);

    // CSR build
    int nb_scan = (N + SCAN_B - 1) / SCAN_B;
    csr_count_kernel<<<(E + 255) / 256, 256, 0, stream>>>(dstp, cntI, E);
    scan1_kernel<<<nb_scan, SCAN_B, 0, stream>>>(cntI, off, bsum, N);
    scan2_kernel<<<1, SCAN_B, 0, stream>>>(bsum, nb_scan);
    scan3_kernel<<<nb_scan, SCAN_B, 0, stream>>>(off, bsum, N);
    csr_fill_kernel<<<(E + 255) / 256, 256, 0, stream>>>(srcp, dstp, pseudo, off, rec, E);

    // conversions / weight prep
    to_bf16_kernel<<<(N * 8 + 255) / 256, 256, 0, stream>>>(x, xb, N * 8);
    build_wt_kernel<KP1, 8,  32,  32 ><<<(32  * KP1 + 255) / 256, 256, 0, stream>>>(W1, r1, WT1);
    build_wt_kernel<KP2, 32, 64,  64 ><<<(64  * KP2 + 255) / 256, 256, 0, stream>>>(W2, r2, WT2);
    build_wt_kernel<KP3, 64, 124, 128><<<(128 * KP3 + 255) / 256, 256, 0, stream>>>(W3, r3, WT3);

    run_layer<8,  32,  32 >(xb, WT1, b1, h1, accB, rec, off, N, avail, stream);
    run_layer<32, 64,  64 >(h1, WT2, b2, h2, accB, rec, off, N, avail, stream);
    run_layer<64, 124, 128>(h2, WT3, b3, h3, accB, rec, off, N, avail, stream);

    graph_reduce_kernel<<<(N + GS_CH - 1) / GS_CH, 128, 0, stream>>>(h3, batch, gbuf, N);
    batch_count_kernel<<<(N + 255) / 256, 256, 0, stream>>>(batch, cntF, N);
    head_kernel<<<64, 64, 0, stream>>>(gbuf, cntF, fcw, fcb, (float*)d_out);
}